// Round 2
// baseline (164.640 us; speedup 1.0000x reference)
//
#include <hip/hip_runtime.h>

// class_aware_rgat — MI355X fused kernel (round 1: infra retry + ILP hardening).
//
// Reference's softmax is over a size-1 axis => attn == 1, so the MLP path
// (dxEmb, W1/b1/W2/b2, tanh) is dead code. Live math per output row i,
// v = permute_index[i]:
//   coe  = dot(classEmb[leaves[v,0]], Wc) + bc
//   out[i] = sum_l anEmbTab[ancestors[v,l]] + coe * sum_l reEmb[relations[v,l]]
//   out[i] = 0 when v == V (the appended zero row)
//
// One 64-lane wave per output row; float2 per lane (64*8B = 512B row).
// All 16 row-gathers are issued before the reduction so the wave keeps
// ~16 global loads in flight (latency hiding if we're latency-bound).

#define RG_V  50000
#define RG_L  8

__global__ __launch_bounds__(256) void rgat_fused_kernel(
    const float* __restrict__ classEmb,   // (V+1, 128)
    const float* __restrict__ reEmb,      // (17, 128)
    const float* __restrict__ anEmbTab,   // (V+NA+1, 128)
    const float* __restrict__ Wc,         // (128,)
    const float* __restrict__ bc,         // (1,)
    const int*  __restrict__ leaves,      // (V, 8)
    const int*  __restrict__ ancestors,   // (V, 8)
    const int*  __restrict__ relations,   // (V, 8)
    const int*  __restrict__ perm,        // (V+1,)
    float*      __restrict__ out)         // (V+1, 128)
{
    const int row  = blockIdx.x * 4 + (threadIdx.x >> 6);   // 4 waves/block
    if (row > RG_V) return;
    const int lane = threadIdx.x & 63;

    float2* outp = reinterpret_cast<float2*>(out) + row * 64 + lane;

    const int v = perm[row];
    if (v >= RG_V) {                 // v == V -> appended zero row
        *outp = make_float2(0.f, 0.f);
        return;
    }

    // ---- indices (two 16B loads per table; base is v*8 ints = 32B aligned) ----
    const int4 a0 = reinterpret_cast<const int4*>(ancestors + v * RG_L)[0];
    const int4 a1 = reinterpret_cast<const int4*>(ancestors + v * RG_L)[1];
    const int4 r0 = reinterpret_cast<const int4*>(relations + v * RG_L)[0];
    const int4 r1 = reinterpret_cast<const int4*>(relations + v * RG_L)[1];
    const int lv0 = leaves[v * RG_L];
    const int anc[8] = {a0.x, a0.y, a0.z, a0.w, a1.x, a1.y, a1.z, a1.w};
    const int rel[8] = {r0.x, r0.y, r0.z, r0.w, r1.x, r1.y, r1.z, r1.w};

    const float2* anT = reinterpret_cast<const float2*>(anEmbTab);
    const float2* reT = reinterpret_cast<const float2*>(reEmb);

    // ---- issue ALL gathers up front (16 row-gathers + classEmb + Wc) ----
    float2 aL[RG_L], rL[RG_L];
    #pragma unroll
    for (int l = 0; l < RG_L; ++l) aL[l] = anT[anc[l] * 64 + lane];
    #pragma unroll
    for (int l = 0; l < RG_L; ++l) rL[l] = reT[rel[l] * 64 + lane];
    const float2 c = reinterpret_cast<const float2*>(classEmb)[lv0 * 64 + lane];
    const float2 w = reinterpret_cast<const float2*>(Wc)[lane];

    // ---- class coefficient: wave-wide 128-elem dot ----
    float partial = c.x * w.x + c.y * w.y;
    #pragma unroll
    for (int off = 32; off >= 1; off >>= 1)
        partial += __shfl_xor(partial, off, 64);
    const float coe = partial + bc[0];

    // ---- reduce (coe factored out of the relation sum) ----
    float2 accA = make_float2(0.f, 0.f);
    float2 accR = make_float2(0.f, 0.f);
    #pragma unroll
    for (int l = 0; l < RG_L; ++l) {
        accA.x += aL[l].x;  accA.y += aL[l].y;
        accR.x += rL[l].x;  accR.y += rL[l].y;
    }

    *outp = make_float2(accA.x + coe * accR.x,
                        accA.y + coe * accR.y);
}

extern "C" void kernel_launch(void* const* d_in, const int* in_sizes, int n_in,
                              void* d_out, int out_size, void* d_ws, size_t ws_size,
                              hipStream_t stream) {
    // setup_inputs() order:
    // 0 dxEmb (dead), 1 classEmb, 2 reEmb, 3 anEmbTab, 4 W1 (dead), 5 b1 (dead),
    // 6 W2 (dead), 7 b2 (dead), 8 Wc, 9 bc, 10 leaves, 11 ancestors,
    // 12 relations, 13 permute_index
    const float* classEmb  = (const float*)d_in[1];
    const float* reEmb     = (const float*)d_in[2];
    const float* anEmbTab  = (const float*)d_in[3];
    const float* Wc        = (const float*)d_in[8];
    const float* bc        = (const float*)d_in[9];
    const int*   leaves    = (const int*)d_in[10];
    const int*   ancestors = (const int*)d_in[11];
    const int*   relations = (const int*)d_in[12];
    const int*   perm      = (const int*)d_in[13];
    float*       out       = (float*)d_out;

    const int rows   = RG_V + 1;            // 50001 output rows
    const int blocks = (rows + 3) / 4;      // 4 waves (rows) per 256-thread block

    rgat_fused_kernel<<<blocks, 256, 0, stream>>>(
        classEmb, reEmb, anEmbTab, Wc, bc,
        leaves, ancestors, relations, perm, out);
}

// Round 5
// 155.158 us; speedup vs baseline: 1.0611x; 1.0611x over previous
//
#include <hip/hip_runtime.h>

// class_aware_rgat — MI355X fused kernel (round 4: resubmit; rounds 2-3 never
// ran — GPUAcquisitionTimeout at the broker, no measurement yet).
//
// Live math (softmax over size-1 axis == 1, MLP path dead):
//   v = perm[i];  out[i] = sum_l anEmbTab[anc[v,l]] + coe(v) * sum_l reEmb[rel[v,l]]
//   coe(v) = dot(classEmb[leaves[v,0]], Wc) + bc ;  out[i] = 0 if v == V
//
// Round-1 counters: 50 us, HBM 34%, VALU 20%, occ 71% -> latency/MLP-bound.
// This kernel: 2 rows/wave, float4 (16B/lane) gathers pairing 2 embedding rows
// per instruction (1KiB/instr), nontemporal 1KiB full-wave stores.

#define RG_V  50000
#define RG_L  8

typedef float f32x4_native __attribute__((ext_vector_type(4)));

__device__ __forceinline__ float4 f4add(float4 a, float4 b) {
    return make_float4(a.x + b.x, a.y + b.y, a.z + b.z, a.w + b.w);
}
__device__ __forceinline__ float4 f4fma(float s, float4 a, float4 b) {
    return make_float4(fmaf(s, a.x, b.x), fmaf(s, a.y, b.y),
                       fmaf(s, a.z, b.z), fmaf(s, a.w, b.w));
}
__device__ __forceinline__ float4 shfl_xor32_f4(float4 x) {
    return make_float4(__shfl_xor(x.x, 32, 64), __shfl_xor(x.y, 32, 64),
                       __shfl_xor(x.z, 32, 64), __shfl_xor(x.w, 32, 64));
}

__global__ __launch_bounds__(256) void rgat_fused_kernel(
    const float* __restrict__ classEmb,   // (V+1, 128)
    const float* __restrict__ reEmb,      // (17, 128)
    const float* __restrict__ anEmbTab,   // (V+NA+1, 128)
    const float* __restrict__ Wc,         // (128,)
    const float* __restrict__ bc,         // (1,)
    const int*  __restrict__ leaves,      // (V, 8)
    const int*  __restrict__ ancestors,   // (V, 8)
    const int*  __restrict__ relations,   // (V, 8)
    const int*  __restrict__ perm,        // (V+1,)
    float*      __restrict__ out)         // (V+1, 128)
{
    const int wid  = blockIdx.x * 4 + (threadIdx.x >> 6);   // wave id
    const int row0 = wid * 2;                                // this wave: rows row0, row0+1
    if (row0 > RG_V) return;
    const int lane = threadIdx.x & 63;
    const int h    = lane >> 5;        // half: 0 = even-parity gathers/row0 out, 1 = odd/row1
    const int li   = lane & 31;        // float4 column within a 128-float row
    const bool have1 = (row0 + 1 <= RG_V);

    const int p0 = perm[row0];
    const int p1 = have1 ? perm[row0 + 1] : 0;
    const bool valid0 = (p0 < RG_V);
    const bool valid1 = have1 && (p1 < RG_V);
    const int v0 = valid0 ? p0 : 0;    // dummy row 0 for the zero-row case
    const int v1 = valid1 ? p1 : 0;

    // ---- index loads (16B each; base v*8 ints is 32B-aligned) ----
    const int4* anc4 = reinterpret_cast<const int4*>(ancestors);
    const int4* rel4 = reinterpret_cast<const int4*>(relations);
    const int4 a00 = anc4[v0 * 2], a01 = anc4[v0 * 2 + 1];
    const int4 a10 = anc4[v1 * 2], a11 = anc4[v1 * 2 + 1];
    const int4 r00 = rel4[v0 * 2], r01 = rel4[v0 * 2 + 1];
    const int4 r10 = rel4[v1 * 2], r11 = rel4[v1 * 2 + 1];
    const int lv0 = leaves[v0 * RG_L];
    const int lv1 = leaves[v1 * RG_L];

    // per-lane parity selection (explicit ?: so nothing runtime-indexes an array)
    const int ia00 = h ? a00.y : a00.x, ia01 = h ? a00.w : a00.z;
    const int ia02 = h ? a01.y : a01.x, ia03 = h ? a01.w : a01.z;
    const int ia10 = h ? a10.y : a10.x, ia11 = h ? a10.w : a10.z;
    const int ia12 = h ? a11.y : a11.x, ia13 = h ? a11.w : a11.z;
    const int ir00 = h ? r00.y : r00.x, ir01 = h ? r00.w : r00.z;
    const int ir02 = h ? r01.y : r01.x, ir03 = h ? r01.w : r01.z;
    const int ir10 = h ? r10.y : r10.x, ir11 = h ? r10.w : r10.z;
    const int ir12 = h ? r11.y : r11.x, ir13 = h ? r11.w : r11.z;

    const float4* anT = reinterpret_cast<const float4*>(anEmbTab);  // row = 32 float4
    const float4* reT = reinterpret_cast<const float4*>(reEmb);
    const float4* clT = reinterpret_cast<const float4*>(classEmb);
    const float4* wcT = reinterpret_cast<const float4*>(Wc);

    // ---- gathers: each instr is full-wave 1KiB covering 2 embedding rows ----
    const float4 gA00 = anT[(size_t)ia00 * 32 + li];
    const float4 gA01 = anT[(size_t)ia01 * 32 + li];
    const float4 gA02 = anT[(size_t)ia02 * 32 + li];
    const float4 gA03 = anT[(size_t)ia03 * 32 + li];
    const float4 gA10 = anT[(size_t)ia10 * 32 + li];
    const float4 gA11 = anT[(size_t)ia11 * 32 + li];
    const float4 gA12 = anT[(size_t)ia12 * 32 + li];
    const float4 gA13 = anT[(size_t)ia13 * 32 + li];
    const float4 gR00 = reT[(size_t)ir00 * 32 + li];
    const float4 gR01 = reT[(size_t)ir01 * 32 + li];
    const float4 gR02 = reT[(size_t)ir02 * 32 + li];
    const float4 gR03 = reT[(size_t)ir03 * 32 + li];
    const float4 gR10 = reT[(size_t)ir10 * 32 + li];
    const float4 gR11 = reT[(size_t)ir11 * 32 + li];
    const float4 gR12 = reT[(size_t)ir12 * 32 + li];
    const float4 gR13 = reT[(size_t)ir13 * 32 + li];
    // class-coefficient operands (per-half row)
    const float4 c4 = clT[(size_t)(h ? lv1 : lv0) * 32 + li];
    const float4 w4 = wcT[li];

    // ---- parity-partial sums (own half's 4 of 8 rows) ----
    float4 accA0 = f4add(f4add(gA00, gA01), f4add(gA02, gA03));
    float4 accA1 = f4add(f4add(gA10, gA11), f4add(gA12, gA13));
    float4 accR0 = f4add(f4add(gR00, gR01), f4add(gR02, gR03));
    float4 accR1 = f4add(f4add(gR10, gR11), f4add(gR12, gR13));

    // ---- per-half dot(classEmb[leaf0], Wc): 32-lane butterfly within half ----
    float part = c4.x * w4.x + c4.y * w4.y + c4.z * w4.z + c4.w * w4.w;
    #pragma unroll
    for (int off = 16; off >= 1; off >>= 1)
        part += __shfl_xor(part, off, 64);
    const float coe = part + bc[0];              // coefficient for own half's row

    // ---- merge parities: one 32-xor swap serves both rows ----
    // h=0 lanes hold (A0 even-part, A1 even-part); they need A0's odd part.
    float4 oxA = shfl_xor32_f4(h ? accA0 : accA1);
    float4 oxR = shfl_xor32_f4(h ? accR0 : accR1);
    float4 myA = f4add(h ? accA1 : accA0, oxA);  // full 8-row ancestor sum, own row
    float4 myR = f4add(h ? accR1 : accR0, oxR);  // full 8-row relation sum, own row

    float4 res = f4fma(coe, myR, myA);
    const bool validOwn = h ? valid1 : valid0;
    if (!validOwn) res = make_float4(0.f, 0.f, 0.f, 0.f);

    // ---- full-wave contiguous 1KiB nontemporal store (rows row0, row0+1) ----
    if (h == 0 || have1) {
        float4* dst = reinterpret_cast<float4*>(out) + (size_t)row0 * 32 + lane;
        __builtin_nontemporal_store(*reinterpret_cast<f32x4_native*>(&res),
                                    reinterpret_cast<f32x4_native*>(dst));
    }
}

extern "C" void kernel_launch(void* const* d_in, const int* in_sizes, int n_in,
                              void* d_out, int out_size, void* d_ws, size_t ws_size,
                              hipStream_t stream) {
    // 0 dxEmb (dead), 1 classEmb, 2 reEmb, 3 anEmbTab, 4-7 W1/b1/W2/b2 (dead),
    // 8 Wc, 9 bc, 10 leaves, 11 ancestors, 12 relations, 13 permute_index
    const float* classEmb  = (const float*)d_in[1];
    const float* reEmb     = (const float*)d_in[2];
    const float* anEmbTab  = (const float*)d_in[3];
    const float* Wc        = (const float*)d_in[8];
    const float* bc        = (const float*)d_in[9];
    const int*   leaves    = (const int*)d_in[10];
    const int*   ancestors = (const int*)d_in[11];
    const int*   relations = (const int*)d_in[12];
    const int*   perm      = (const int*)d_in[13];
    float*       out       = (float*)d_out;

    const int waves  = (RG_V + 1 + 1) / 2;       // 2 rows per wave -> 25001 waves
    const int blocks = (waves + 3) / 4;          // 4 waves per 256-thread block

    rgat_fused_kernel<<<blocks, 256, 0, stream>>>(
        classEmb, reEmb, anEmbTab, Wc, bc,
        leaves, ancestors, relations, perm, out);
}